// Round 8
// baseline (705.583 us; speedup 1.0000x reference)
//
#include <hip/hip_runtime.h>
#include <hip/hip_bf16.h>
#include <cstdint>
#include <cstddef>

#define B_ 4
#define S_ 2048
#define E_ 1024
#define H_ 16
#define D_ 64
#define NEG_BIG (-1e30f)
#define SC2 0.18033688011112043f   /* 0.125 * log2(e) */

typedef __bf16 bf16x8 __attribute__((ext_vector_type(8)));
typedef __bf16 bf16x4v __attribute__((ext_vector_type(4)));
typedef float f32x4 __attribute__((ext_vector_type(4)));

__device__ __forceinline__ void async_copy16(void* lds, const void* g) {
  __builtin_amdgcn_global_load_lds(
      (const __attribute__((address_space(1))) void*)g,
      (__attribute__((address_space(3))) void*)lds, 16, 0, 0);
}

__device__ __forceinline__ float bfu2f(unsigned short u) {
  unsigned v = ((unsigned)u) << 16;
  float f;
  __builtin_memcpy(&f, &v, 4);
  return f;
}
__device__ __forceinline__ unsigned short f2bfu(float f) {
  __hip_bfloat16 h = __float2bfloat16(f);  // RNE
  unsigned short u;
  __builtin_memcpy(&u, &h, 2);
  return u;
}
__device__ __forceinline__ unsigned pk2(float a, float b) {
  return (unsigned)f2bfu(a) | ((unsigned)f2bfu(b) << 16);
}

// ---------------- dtype probe (proven) ----------------
__global__ __launch_bounds__(256) void probe_dtype(
    const unsigned short* __restrict__ xr, int* __restrict__ flagp) {
  __shared__ int cnt;
  if (threadIdx.x == 0) cnt = 0;
  __syncthreads();
  int bad = 0;
  for (int i = 0; i < 32; ++i) {
    unsigned short u = xr[(threadIdx.x * 32 + i) * 2];
    int e = (u >> 7) & 0xFF;
    if (e == 0xFF || e >= 0x90 || (e != 0 && e <= 0x60)) bad++;
  }
  atomicAdd(&cnt, bad);
  __syncthreads();
  if (threadIdx.x == 0) *flagp = (cnt > 512) ? 0 : 1;  // 0=fp32, 1=bf16
}

__global__ __launch_bounds__(256) void convert_to_f32(
    const void* __restrict__ in, float* __restrict__ out,
    const int* __restrict__ flagp, int n) {
  int i = blockIdx.x * blockDim.x + threadIdx.x;
  if (i >= n) return;
  out[i] = (*flagp == 0) ? ((const float*)in)[i]
                         : bfu2f(((const unsigned short*)in)[i]);
}

// pad mask -> additive bias (0 / -1e30)
__global__ __launch_bounds__(256) void mask_bias(
    const int* __restrict__ am, float* __restrict__ mb, int n) {
  int i = blockIdx.x * blockDim.x + threadIdx.x;
  if (i < n) mb[i] = am[i] ? 0.f : NEG_BIG;
}

// transpose + convert: out_bf16[C][R] = in[R][C]   (proven)
__global__ __launch_bounds__(256) void transpose_conv(
    const void* __restrict__ in, unsigned short* __restrict__ out,
    const int* __restrict__ flagp, int R, int C) {
  __shared__ unsigned short t[32][33];
  const int flag = *flagp;
  const int c0 = blockIdx.x * 32, r0 = blockIdx.y * 32;
  const int lc = threadIdx.x & 31, lr = threadIdx.x >> 5;
  for (int i = 0; i < 4; ++i) {
    int r = lr + i * 8;
    size_t idx = (size_t)(r0 + r) * C + c0 + lc;
    t[r][lc] = (flag == 0) ? f2bfu(((const float*)in)[idx])
                           : ((const unsigned short*)in)[idx];
  }
  __syncthreads();
  for (int i = 0; i < 4; ++i) {
    int r = lr + i * 8;
    out[(size_t)(c0 + r) * R + r0 + lc] = t[lc][r];
  }
}

// -------- V^T build: vtg[bh][d=64][key=2048] <- qkv[.][2048 + h*64 + d] ----
// grid: (S/64, bsz*16), block 256. One 64key x 64d tile per block.
__global__ __launch_bounds__(256) void vt_build(
    const __hip_bfloat16* __restrict__ qkv,   // [bsz*S][3072]
    __hip_bfloat16* __restrict__ vtg) {       // [bsz*16][64][2048]
  __shared__ unsigned short t[64][72];
  const int tid = threadIdx.x;
  const int k0 = blockIdx.x * 64;
  const int bh = blockIdx.y;
  const int h = bh & 15;
  const size_t rowbase = (size_t)(bh >> 4) * S_;
  const int row = tid >> 2, c = tid & 3;
  {
    const __hip_bfloat16* src = qkv + (rowbase + k0 + row) * 3072 + 2048 + h * 64;
    uint4 v0 = *(const uint4*)(src + c * 8);
    uint4 v1 = *(const uint4*)(src + (c + 4) * 8);
    *(uint4*)&t[row][c * 8] = v0;
    *(uint4*)&t[row][(c + 4) * 8] = v1;
  }
  __syncthreads();
  {
    const int d = row;  // 0..63
    __hip_bfloat16* dst = vtg + ((size_t)bh * 64 + d) * 2048 + k0;
    unsigned short tmp[8];
    for (int i = 0; i < 8; ++i) tmp[i] = t[c * 8 + i][d];
    *(uint4*)&tmp[0];  // no-op keep
    *(uint4*)(dst + c * 8) = *(uint4*)tmp;
    for (int i = 0; i < 8; ++i) tmp[i] = t[(c + 4) * 8 + i][d];
    *(uint4*)(dst + (c + 4) * 8) = *(uint4*)tmp;
  }
}

// -------- GEMM1: qkv = x(fp32|bf16) @ WqkvT^T + bias, out bf16 (proven r7) --
__global__ __launch_bounds__(256) void gemm_x_w(
    const void* __restrict__ Xin, long long xoff,
    const __hip_bfloat16* __restrict__ Bt,
    const float* __restrict__ bias,
    const int* __restrict__ flagp,
    __hip_bfloat16* __restrict__ C,
    int M, int N, int K) {
  __shared__ __align__(16) __hip_bfloat16 As[128 * 32];
  __shared__ __align__(16) __hip_bfloat16 Bs[128 * 32];
  const int flag = *flagp;
  const int tid = threadIdx.x;
  const int m0 = blockIdx.x * 128, n0 = blockIdx.y * 128;
  const int w = tid >> 6, lane = tid & 63;
  const int wm = (w & 1) * 64, wn = (w >> 1) * 64;
  const int lm = lane & 15, kg = lane >> 4;
  const int e0 = tid * 8, e1 = tid * 8 + 2048;
  const int ra = tid >> 2;
  const int sw = ((tid >> 3) & 3);
  const int ca = ((tid & 3) ^ sw) * 8;

  f32x4 acc[4][4] = {};

  for (int k0 = 0; k0 < K; k0 += 32) {
    uint4 aw0, aw1;
    if (flag == 0) {
      const float* A32 = (const float*)Xin + xoff;
      float4 f0 = *(const float4*)(A32 + (size_t)(m0 + ra) * K + k0 + ca);
      float4 f1 = *(const float4*)(A32 + (size_t)(m0 + ra) * K + k0 + ca + 4);
      float4 f2 = *(const float4*)(A32 + (size_t)(m0 + ra + 64) * K + k0 + ca);
      float4 f3 = *(const float4*)(A32 + (size_t)(m0 + ra + 64) * K + k0 + ca + 4);
      aw0 = make_uint4(pk2(f0.x, f0.y), pk2(f0.z, f0.w), pk2(f1.x, f1.y), pk2(f1.z, f1.w));
      aw1 = make_uint4(pk2(f2.x, f2.y), pk2(f2.z, f2.w), pk2(f3.x, f3.y), pk2(f3.z, f3.w));
    } else {
      const unsigned short* A16 = (const unsigned short*)Xin + xoff;
      aw0 = *(const uint4*)(A16 + (size_t)(m0 + ra) * K + k0 + ca);
      aw1 = *(const uint4*)(A16 + (size_t)(m0 + ra + 64) * K + k0 + ca);
    }
    __syncthreads();
    *(uint4*)(As + e0) = aw0;
    *(uint4*)(As + e1) = aw1;
    for (int c = 0; c < 2; ++c) {
      int o = tid * 16 + c * 4096;
      int row = o >> 6, chp = (o >> 4) & 3;
      int gch = chp ^ ((row >> 1) & 3);
      async_copy16((char*)Bs + o, (const char*)(Bt + (size_t)(n0 + row) * K + k0 + gch * 8));
    }
    __syncthreads();
    bf16x8 af[4], bfrag[4];
    for (int t = 0; t < 4; ++t) {
      int rt = wm + t * 16 + lm;
      int ch = kg ^ ((rt >> 1) & 3);
      af[t] = *(const bf16x8*)(As + rt * 32 + ch * 8);
    }
    for (int t = 0; t < 4; ++t) {
      int rt = wn + t * 16 + lm;
      int ch = kg ^ ((rt >> 1) & 3);
      bfrag[t] = *(const bf16x8*)(Bs + rt * 32 + ch * 8);
    }
    for (int tm = 0; tm < 4; ++tm)
      for (int tn = 0; tn < 4; ++tn)
        acc[tm][tn] = __builtin_amdgcn_mfma_f32_16x16x32_bf16(af[tm], bfrag[tn], acc[tm][tn], 0, 0, 0);
  }

  for (int tn = 0; tn < 4; ++tn) {
    int col = n0 + wn + tn * 16 + lm;
    float bv = bias[col];
    for (int tm = 0; tm < 4; ++tm) {
      int rbase = m0 + wm + tm * 16 + kg * 4;
      for (int r = 0; r < 4; ++r)
        C[(size_t)(rbase + r) * N + col] = __float2bfloat16(acc[tm][tn][r] + bv);
    }
  }
}

// -------- GEMM2: out = attno @ WprojT^T + bias; out dtype by flag (r7) -----
__global__ __launch_bounds__(256) void gemm_p_out(
    const __hip_bfloat16* __restrict__ A,
    const __hip_bfloat16* __restrict__ Bt,
    const float* __restrict__ bias,
    const int* __restrict__ flagp,
    void* __restrict__ Cv, long long coff,
    int M, int N, int K) {
  __shared__ __align__(16) __hip_bfloat16 As[128 * 32];
  __shared__ __align__(16) __hip_bfloat16 Bs[128 * 32];
  const int flag = *flagp;
  const int tid = threadIdx.x;
  const int m0 = blockIdx.x * 128, n0 = blockIdx.y * 128;
  const int w = tid >> 6, lane = tid & 63;
  const int wm = (w & 1) * 64, wn = (w >> 1) * 64;
  const int lm = lane & 15, kg = lane >> 4;

  f32x4 acc[4][4] = {};

  for (int k0 = 0; k0 < K; k0 += 32) {
    __syncthreads();
    for (int c = 0; c < 2; ++c) {
      int o = tid * 16 + c * 4096;
      int row = o >> 6, chp = (o >> 4) & 3;
      int gch = chp ^ ((row >> 1) & 3);
      async_copy16((char*)As + o, (const char*)(A + (size_t)(m0 + row) * K + k0 + gch * 8));
      async_copy16((char*)Bs + o, (const char*)(Bt + (size_t)(n0 + row) * K + k0 + gch * 8));
    }
    __syncthreads();
    bf16x8 af[4], bfrag[4];
    for (int t = 0; t < 4; ++t) {
      int rt = wm + t * 16 + lm;
      int ch = kg ^ ((rt >> 1) & 3);
      af[t] = *(const bf16x8*)(As + rt * 32 + ch * 8);
    }
    for (int t = 0; t < 4; ++t) {
      int rt = wn + t * 16 + lm;
      int ch = kg ^ ((rt >> 1) & 3);
      bfrag[t] = *(const bf16x8*)(Bs + rt * 32 + ch * 8);
    }
    for (int tm = 0; tm < 4; ++tm)
      for (int tn = 0; tn < 4; ++tn)
        acc[tm][tn] = __builtin_amdgcn_mfma_f32_16x16x32_bf16(af[tm], bfrag[tn], acc[tm][tn], 0, 0, 0);
  }

  for (int tn = 0; tn < 4; ++tn) {
    int col = n0 + wn + tn * 16 + lm;
    float bv = bias[col];
    for (int tm = 0; tm < 4; ++tm) {
      int rbase = m0 + wm + tm * 16 + kg * 4;
      for (int r = 0; r < 4; ++r) {
        float v = acc[tm][tn][r] + bv;
        size_t idx = (size_t)coff + (size_t)(rbase + r) * N + col;
        if (flag == 0) ((float*)Cv)[idx] = v;
        else           ((unsigned short*)Cv)[idx] = f2bfu(v);
      }
    }
  }
}

// -------- causal flash attention v4: barrier-free, per-wave autonomous -----
// grid: (S/64 = 32 bands, bsz*16). block 256 = 4 waves; wave w owns the 16-q
// tile q0 = band*64 + w*16. K frags read directly from qkv (L2-cached);
// V^T frags from vtg. Only wave-private Ps goes through LDS (in-order DS,
// no __syncthreads anywhere).
#define VSTR 72
__global__ __launch_bounds__(256, 4) void attn_flash(
    const __hip_bfloat16* __restrict__ qkv,  // [bsz*S][3072]
    const __hip_bfloat16* __restrict__ vtg,  // [bsz*16][64][2048]
    const float* __restrict__ mbias,         // [bsz*S] 0 / -1e30
    __hip_bfloat16* __restrict__ outp) {     // [bsz*S][1024]
  __shared__ __align__(16) __hip_bfloat16 Ps[4][16 * VSTR];

  const int tid = threadIdx.x;
  const int band = (gridDim.x - 1) - blockIdx.x;   // LPT: heavy first
  const int bh = blockIdx.y;
  const int h = bh & 15;
  const size_t rowbase = (size_t)(bh >> 4) * S_;
  const int w = tid >> 6, lane = tid & 63;
  const int lm = lane & 15, kg = lane >> 4;
  const int qg = band * 64 + w * 16 + lm;          // this lane's q
  __hip_bfloat16* PsW = Ps[w];

  // Q fragments (B-operand of S^T = K·Q^T), persistent
  const __hip_bfloat16* qrow = qkv + (rowbase + qg) * 3072 + h * 64;
  bf16x8 bq0 = *(const bf16x8*)(qrow + kg * 8);
  bf16x8 bq1 = *(const bf16x8*)(qrow + 32 + kg * 8);

  float mrow = NEG_BIG, plocal = 0.f;
  f32x4 oacc[4] = {};   // O^T[d][q]: col q=lm, row d = ct2*16 + kg*4 + r

  const __hip_bfloat16* kbase = qkv + rowbase * 3072 + 1024 + h * 64;
  const __hip_bfloat16* vbase = vtg + (size_t)bh * 64 * 2048;

  for (int j = 0; j <= band; ++j) {
    const int j0 = j * 64;
    // K fragments: 8 global dwordx4 (16 distinct 64B lines each; L2-hit)
    bf16x8 kf[2][4];
    #pragma unroll
    for (int ks = 0; ks < 2; ++ks)
      #pragma unroll
      for (int ct = 0; ct < 4; ++ct)
        kf[ks][ct] = *(const bf16x8*)(kbase + (size_t)(j0 + ct * 16 + lm) * 3072 + ks * 32 + kg * 8);
    float4 mb[4];
    #pragma unroll
    for (int ct = 0; ct < 4; ++ct)
      mb[ct] = *(const float4*)(mbias + rowbase + j0 + ct * 16 + kg * 4);

    // S^T = K · Q^T
    f32x4 sacc[4] = {};
    #pragma unroll
    for (int ks = 0; ks < 2; ++ks) {
      bf16x8 bq = ks ? bq1 : bq0;
      #pragma unroll
      for (int ct = 0; ct < 4; ++ct)
        sacc[ct] = __builtin_amdgcn_mfma_f32_16x16x32_bf16(kf[ks][ct], bq, sacc[ct], 0, 0, 0);
    }
    // V^T fragments (issued before softmax so latency hides under VALU)
    bf16x8 vf[2][4];
    #pragma unroll
    for (int ks = 0; ks < 2; ++ks)
      #pragma unroll
      for (int ct2 = 0; ct2 < 4; ++ct2)
        vf[ks][ct2] = *(const bf16x8*)(vbase + (size_t)(ct2 * 16 + lm) * 2048 + j0 + ks * 32 + kg * 8);

    // softmax (log2 domain)
    float mt = NEG_BIG;
    if (j == band) {  // diagonal tile: per-element causal (block-uniform)
      #pragma unroll
      for (int ct = 0; ct < 4; ++ct) {
        const float* mp = (const float*)&mb[ct];
        #pragma unroll
        for (int r = 0; r < 4; ++r) {
          int keyg = j0 + ct * 16 + kg * 4 + r;
          float v = fmaf(sacc[ct][r], SC2, mp[r]);
          v = (keyg <= qg) ? v : NEG_BIG;
          sacc[ct][r] = v;
          mt = fmaxf(mt, v);
        }
      }
    } else {
      #pragma unroll
      for (int ct = 0; ct < 4; ++ct) {
        const float* mp = (const float*)&mb[ct];
        #pragma unroll
        for (int r = 0; r < 4; ++r) {
          float v = fmaf(sacc[ct][r], SC2, mp[r]);
          sacc[ct][r] = v;
          mt = fmaxf(mt, v);
        }
      }
    }
    mt = fmaxf(mt, __shfl_xor(mt, 16));
    mt = fmaxf(mt, __shfl_xor(mt, 32));
    const float mn = fmaxf(mrow, mt);
    const float a = __builtin_exp2f(mrow - mn);  // first iter: 0
    float psl = 0.f;
    #pragma unroll
    for (int ct = 0; ct < 4; ++ct) {
      float p0 = __builtin_exp2f(sacc[ct][0] - mn), p1 = __builtin_exp2f(sacc[ct][1] - mn);
      float p2 = __builtin_exp2f(sacc[ct][2] - mn), p3 = __builtin_exp2f(sacc[ct][3] - mn);
      psl += (p0 + p1) + (p2 + p3);
      bf16x4v pv;
      pv[0] = (__bf16)p0; pv[1] = (__bf16)p1; pv[2] = (__bf16)p2; pv[3] = (__bf16)p3;
      *(bf16x4v*)(PsW + lm * VSTR + ct * 16 + kg * 4) = pv;  // P[q=lm][keys]
    }
    plocal = plocal * a + psl;
    mrow = mn;
    #pragma unroll
    for (int ct2 = 0; ct2 < 4; ++ct2) {
      oacc[ct2][0] *= a; oacc[ct2][1] *= a;
      oacc[ct2][2] *= a; oacc[ct2][3] *= a;
    }
    // O^T += V^T · P  (B=Ps wave-private; same-wave DS in-order)
    #pragma unroll
    for (int ks = 0; ks < 2; ++ks) {
      bf16x8 bp = *(const bf16x8*)(PsW + lm * VSTR + ks * 32 + kg * 8);
      #pragma unroll
      for (int ct2 = 0; ct2 < 4; ++ct2)
        oacc[ct2] = __builtin_amdgcn_mfma_f32_16x16x32_bf16(vf[ks][ct2], bp, oacc[ct2], 0, 0, 0);
    }
  }

  {  // epilogue
    float l = plocal;
    l += __shfl_xor(l, 16);
    l += __shfl_xor(l, 32);
    float linv = (l > 0.f) ? 1.f / l : 0.f;
    __hip_bfloat16* ob = outp + (rowbase + qg) * 1024 + h * 64;
    #pragma unroll
    for (int ct2 = 0; ct2 < 4; ++ct2) {
      bf16x4v ov;
      ov[0] = (__bf16)(oacc[ct2][0] * linv);
      ov[1] = (__bf16)(oacc[ct2][1] * linv);
      ov[2] = (__bf16)(oacc[ct2][2] * linv);
      ov[3] = (__bf16)(oacc[ct2][3] * linv);
      *(bf16x4v*)(ob + ct2 * 16 + kg * 4) = ov;
    }
  }
}

extern "C" void kernel_launch(void* const* d_in, const int* in_sizes, int n_in,
                              void* d_out, int out_size, void* d_ws, size_t ws_size,
                              hipStream_t stream) {
  // pre = 8454144 B: flag | bq | bp | mbias | WqkvT 6MB | WprojT 2MB
  // tiers: full  (ws >= 92340224): qkv 48M + attno 16M + vtg 16M, 1 attn pass
  //        mid   (ws >= 83886080): qkv 48M + attno 16M + vtg 4M, 4 attn passes
  //        small (else):           qkv 12M + attno 4M + vtg 4M, per-batch all
  const size_t PRE = 8454144;
  const bool merged = (ws_size >= 83886080ull);
  const bool vtg_full = (ws_size >= PRE + 50331648ull + 16777216ull + 16777216ull);
  char* ws = (char*)d_ws;
  int*            flag   = (int*)ws;
  float*          bq     = (float*)(ws + 1024);
  float*          bp     = (float*)(ws + 16384);
  float*          mbias  = (float*)(ws + 32768);
  unsigned short* WqkvTu = (unsigned short*)(ws + 65536);
  unsigned short* WprojTu= (unsigned short*)(ws + 65536 + 6291456);
  char*           big    = ws + PRE;
  __hip_bfloat16* qkv    = (__hip_bfloat16*)big;
  __hip_bfloat16* attno  = (__hip_bfloat16*)(big + (merged ? 50331648u : 12582912u));
  __hip_bfloat16* vtg    = (__hip_bfloat16*)(big + (merged ? 50331648u + 16777216u
                                                           : 12582912u + 4194304u));

  probe_dtype<<<1, 256, 0, stream>>>((const unsigned short*)d_in[0], flag);
  convert_to_f32<<<12, 256, 0, stream>>>(d_in[3], bq, flag, 3072);
  convert_to_f32<<<4, 256, 0, stream>>>(d_in[5], bp, flag, 1024);
  mask_bias<<<(B_ * S_) / 256, 256, 0, stream>>>((const int*)d_in[1], mbias, B_ * S_);
  transpose_conv<<<dim3(96, 32), 256, 0, stream>>>(d_in[2], WqkvTu, flag, 1024, 3072);
  transpose_conv<<<dim3(32, 32), 256, 0, stream>>>(d_in[4], WprojTu, flag, 1024, 1024);

  const int nchunk = merged ? 1 : B_;
  const int bsz = merged ? B_ : 1;
  const int Mc = bsz * S_;
  for (int c = 0; c < nchunk; ++c) {
    long long off = (long long)c * S_ * E_;
    gemm_x_w<<<dim3(Mc / 128, 3072 / 128), 256, 0, stream>>>(
        d_in[0], off, (const __hip_bfloat16*)WqkvTu, bq, flag, qkv, Mc, 3072, 1024);
    if (merged && vtg_full) {
      vt_build<<<dim3(S_ / 64, B_ * 16), 256, 0, stream>>>(qkv, vtg);
      attn_flash<<<dim3(S_ / 64, B_ * 16), 256, 0, stream>>>(qkv, vtg, mbias, attno);
    } else if (merged) {
      for (int bb = 0; bb < B_; ++bb) {  // vtg holds one batch at a time
        const __hip_bfloat16* qkv_b = qkv + (size_t)bb * S_ * 3072;
        vt_build<<<dim3(S_ / 64, 16), 256, 0, stream>>>(qkv_b, vtg);
        attn_flash<<<dim3(S_ / 64, 16), 256, 0, stream>>>(
            qkv_b, vtg, mbias + (size_t)bb * S_, attno + (size_t)bb * S_ * 1024);
      }
    } else {
      vt_build<<<dim3(S_ / 64, 16), 256, 0, stream>>>(qkv, vtg);
      attn_flash<<<dim3(S_ / 64, 16), 256, 0, stream>>>(
          qkv, vtg, mbias + (size_t)c * S_, attno);
    }
    gemm_p_out<<<dim3(Mc / 128, 1024 / 128), 256, 0, stream>>>(
        attno, (const __hip_bfloat16*)WprojTu, bp, flag, d_out, off, Mc, 1024, 1024);
  }
}